// Round 3
// 254.660 us; speedup vs baseline: 1.0757x; 1.0757x over previous
//
#include <hip/hip_runtime.h>
#include <math.h>

#define NN 5
#define DD 4000000
#define VV (DD / 4)          // 1,000,000 float4 groups, exact
#define NB1 2048
#define NB3 2048
#define NTHR 256

typedef float f32x4 __attribute__((ext_vector_type(4)));

// d_out layout (floats):
//   m_cor : [0, NN*DD)
//   c_cor : [NN*DD, NN*DD+25)
//   m_ext : [NN*DD+25, 2*NN*DD+25)
//   c_ext : [2*NN*DD+25, 2*NN*DD+50)
//   err   : [2*NN*DD+50]
//   u     : [2*NN*DD+51, 2*NN*DD+51+DD)

__global__ __launch_bounds__(NTHR)
void k_ext(const float* __restrict__ m0, const float* __restrict__ a,
           const float* __restrict__ dtp, float* __restrict__ out,
           double* __restrict__ partials) {
    float p[NN], p_inv[NN];
    {
        float adt = fabsf(dtp[0]);
        const float pw[NN] = {4.5f, 3.5f, 2.5f, 1.5f, 0.5f};
        const float sc[NN] = {24.f, 6.f, 2.f, 1.f, 1.f};
        float l2 = __log2f(adt);
        #pragma unroll
        for (int i = 0; i < NN; i++) {
            float t = exp2f(pw[i] * l2);
            p[i] = t / sc[i];
            p_inv[i] = sc[i] / t;
        }
    }
    float Ap[NN][NN];
    #pragma unroll
    for (int i = 0; i < NN; i++)
        #pragma unroll
        for (int j = 0; j < NN; j++)
            Ap[i][j] = p[i] * a[i * NN + j] * p_inv[j];

    float* m_ext = out + (size_t)NN * DD + 25;

    double acc = 0.0;
    int v = blockIdx.x * NTHR + threadIdx.x;
    const int stride = gridDim.x * NTHR;
    for (; v < VV; v += stride) {
        const int d = v * 4;
        // m0 rows are 16B-aligned (row offset j*DD, DD%4==0).
        // m0 is read exactly once across the whole problem -> nontemporal,
        // keeps L2/L3 space for the m_ext stream that k_cor re-reads.
        float mm[NN][4];
        #pragma unroll
        for (int j = 0; j < NN; j++) {
            f32x4 t = __builtin_nontemporal_load(
                reinterpret_cast<const f32x4*>(m0 + (size_t)j * DD + d));
            mm[j][0] = t.x; mm[j][1] = t.y; mm[j][2] = t.z; mm[j][3] = t.w;
        }
        float me01[2][4];
        #pragma unroll
        for (int i = 0; i < NN; i++) {
            float r[4];
            #pragma unroll
            for (int e = 0; e < 4; e++) {
                float s = 0.f;
                #pragma unroll
                for (int j = 0; j < NN; j++) s = fmaf(Ap[i][j], mm[j][e], s);
                r[e] = s;
                if (i < 2) me01[i][e] = s;
            }
            // m_ext row base is misaligned by 1 float; align-4 16B store is HW-ok.
            // Plain (cached) store: k_cor re-reads this from L2/L3.
            __builtin_memcpy(m_ext + (size_t)i * DD + d, r, 16);
        }
        #pragma unroll
        for (int e = 0; e < 4; e++) {
            float bias = me01[1][e] - sinf(me01[0][e]);
            acc += (double)bias * (double)bias;
        }
    }

    #pragma unroll
    for (int off = 32; off > 0; off >>= 1) acc += __shfl_down(acc, off, 64);
    __shared__ double sdata[NTHR / 64];
    if ((threadIdx.x & 63) == 0) sdata[threadIdx.x >> 6] = acc;
    __syncthreads();
    if (threadIdx.x == 0) {
        double b = 0.0;
        for (int w = 0; w < NTHR / 64; w++) b += sdata[w];
        partials[blockIdx.x] = b;
    }
}

__global__ void k_scalar(const float* __restrict__ c0, const float* __restrict__ a,
                         const float* __restrict__ qup, const float* __restrict__ dtp,
                         const double* __restrict__ partials, int np_,
                         float* __restrict__ out, float* __restrict__ g_ws) {
    __shared__ double sred[256];
    double acc = 0.0;
    for (int i = threadIdx.x; i < np_; i += 256) acc += partials[i];
    sred[threadIdx.x] = acc;
    __syncthreads();
    for (int s = 128; s > 0; s >>= 1) {
        if (threadIdx.x < s) sred[threadIdx.x] += sred[threadIdx.x + s];
        __syncthreads();
    }
    if (threadIdx.x != 0) return;

    double sumsq = sred[0];
    double dt = (double)dtp[0];
    double adt = fabs(dt);
    const double pwd[NN] = {4.5, 3.5, 2.5, 1.5, 0.5};
    const double scd[NN] = {24.0, 6.0, 2.0, 1.0, 1.0};
    double pd[NN], pid[NN];
    for (int i = 0; i < NN; i++) {
        double t = pow(adt, pwd[i]);
        pd[i] = t / scd[i];
        pid[i] = scd[i] / t;
    }
    double s_scal = 0.0;
    for (int j = 0; j < NN; j++) {
        double v = pid[1] * (double)qup[j * NN + 1];
        s_scal += v * v;
    }
    double diffusion = sqrt(sumsq / ((double)DD * s_scal));
    double err = dt * diffusion * sqrt(s_scal);

    double M[10][NN];
    for (int i = 0; i < NN; i++)
        for (int j = 0; j < NN; j++) {
            double b = 0.0;
            for (int k = 0; k < NN; k++)
                b += (double)a[j * NN + k] * pid[k] * (double)c0[k * NN + i];
            M[i][j] = b;
        }
    for (int i = 0; i < NN; i++)
        for (int j = 0; j < NN; j++)
            M[5 + i][j] = diffusion * (double)qup[j * NN + i];

    // Householder QR, LAPACK slarfg sign convention (matches numpy's R signs)
    for (int k = 0; k < NN; k++) {
        double n2 = 0.0;
        for (int i = k; i < 10; i++) n2 += M[i][k] * M[i][k];
        double nrm = sqrt(n2);
        if (nrm > 0.0) {
            double alpha = M[k][k];
            double beta = (alpha >= 0.0) ? -nrm : nrm;
            double tau = (beta - alpha) / beta;
            double scl = 1.0 / (alpha - beta);
            for (int j = k + 1; j < NN; j++) {
                double w = M[k][j];
                for (int i = k + 1; i < 10; i++) w += M[i][k] * scl * M[i][j];
                w *= tau;
                M[k][j] -= w;
                for (int i = k + 1; i < 10; i++) M[i][j] -= M[i][k] * scl * w;
            }
            M[k][k] = beta;
            for (int i = k + 1; i < 10; i++) M[i][k] = 0.0;
        }
    }

    float* c_cor_out = out + (size_t)NN * DD;
    float* c_ext_out = out + (size_t)2 * NN * DD + 25;

    for (int i = 0; i < NN; i++)
        for (int j = 0; j < NN; j++)
            c_ext_out[i * NN + j] = (float)(pd[i] * M[j][i]);

    double ssq[NN], s = 0.0;
    for (int j = 0; j < NN; j++) { ssq[j] = pd[j] * M[1][j]; s += ssq[j] * ssq[j]; }
    double g[NN];
    for (int i = 0; i < NN; i++) {
        double a2 = 0.0;
        for (int j = 0; j < NN; j++) a2 += pd[j] * M[i][j] * ssq[j];
        g[i] = a2 / s;
    }
    for (int i = 0; i < NN; i++)
        for (int j = 0; j < NN; j++)
            c_cor_out[i * NN + j] = (float)(pd[i] * M[j][i] - g[j] * pd[i] * M[1][i]);

    out[(size_t)2 * NN * DD + 50] = (float)err;
    for (int i = 0; i < NN; i++) g_ws[i] = (float)g[i];
}

__global__ __launch_bounds__(NTHR)
void k_cor(float* __restrict__ out, const float* __restrict__ g_ws) {
    float g[NN];
    #pragma unroll
    for (int i = 0; i < NN; i++) g[i] = g_ws[i];
    const float* m_ext = out + (size_t)NN * DD + 25;
    float* m_cor = out;
    float* u = out + (size_t)2 * NN * DD + 51;

    int v = blockIdx.x * NTHR + threadIdx.x;
    const int stride = gridDim.x * NTHR;
    for (; v < VV; v += stride) {
        const int d = v * 4;
        float me[NN][4];
        #pragma unroll
        for (int i = 0; i < NN; i++) {
            float t[4];
            // same grid/block->element mapping as k_ext -> L2/L3 hit expected
            __builtin_memcpy(t, m_ext + (size_t)i * DD + d, 16);  // align-4 ok
            me[i][0] = t[0]; me[i][1] = t[1]; me[i][2] = t[2]; me[i][3] = t[3];
        }
        float bias[4];
        #pragma unroll
        for (int e = 0; e < 4; e++) bias[e] = me[1][e] - sinf(me[0][e]);

        #pragma unroll
        for (int i = 0; i < NN; i++) {
            f32x4 r;
            r.x = me[i][0] - g[i] * bias[0];
            r.y = me[i][1] - g[i] * bias[1];
            r.z = me[i][2] - g[i] * bias[2];
            r.w = me[i][3] - g[i] * bias[3];
            if (i == 0) __builtin_memcpy(u + d, &r, 16);  // u base align-4 only: plain store
            // m_cor rows are 16B-aligned and never re-read -> nontemporal
            __builtin_nontemporal_store(
                r, reinterpret_cast<f32x4*>(m_cor + (size_t)i * DD + d));
        }
    }
}

extern "C" void kernel_launch(void* const* d_in, const int* in_sizes, int n_in,
                              void* d_out, int out_size, void* d_ws, size_t ws_size,
                              hipStream_t stream) {
    const float* m0  = (const float*)d_in[0];
    const float* c0  = (const float*)d_in[1];
    const float* a   = (const float*)d_in[2];
    const float* qup = (const float*)d_in[3];
    const float* dtp = (const float*)d_in[4];
    float* out = (float*)d_out;

    double* partials = (double*)d_ws;                  // NB1 doubles
    float* g_ws = (float*)((char*)d_ws + NB1 * sizeof(double));

    k_ext<<<NB1, NTHR, 0, stream>>>(m0, a, dtp, out, partials);
    k_scalar<<<1, 256, 0, stream>>>(c0, a, qup, dtp, partials, NB1, out, g_ws);
    k_cor<<<NB3, NTHR, 0, stream>>>(out, g_ws);
}